// Round 8
// baseline (200.141 us; speedup 1.0000x reference)
//
#include <hip/hip_runtime.h>
#include <hip/hip_cooperative_groups.h>
#include <stdint.h>

namespace cg = cooperative_groups;

// Problem constants
#define BB   4
#define CCH  256
#define HH   64
#define WWD  64
#define HWSZ 4096          // H*W
#define DGRP 4
#define CG   64            // C / DG
#define KKN  9
#define KT   2304          // C * KK  (k index = kk*256 + c)
#define NND  16384         // B*H*W
#define GNG  32
#define EPSV 1e-5f

// Workspace layout (bytes):
//  colT     bf16 [NND][KT]            @ 0          size 75,497,472
//  Wb       bf16 [256][KT]            @ 75497472   size  1,179,648
//  partials f32  [128][2] (s1,s2)     @ 76677120   size      1,024
#define WS_COLT  0
#define WS_WB    75497472
#define WS_PART  76677120

typedef __attribute__((ext_vector_type(8))) short short8;
typedef __attribute__((ext_vector_type(4))) float f32x4;

__device__ inline unsigned short f2bf(float f) {
    union { float f; unsigned u; } v; v.f = f;
    unsigned u = v.u;
    return (unsigned short)((u + 0x7FFFu + ((u >> 16) & 1u)) >> 16);  // RNE
}

__device__ inline float bflo(unsigned u) {   // low bf16 of a packed u32 -> f32
    union { unsigned u; float f; } v; v.u = u << 16; return v.f;
}
__device__ inline float bfhi(unsigned u) {   // high bf16 -> f32
    union { unsigned u; float f; } v; v.u = u & 0xffff0000u; return v.f;
}

__device__ inline void gl_lds16(const void* g, void* l) {
    __builtin_amdgcn_global_load_lds(
        (const __attribute__((address_space(1))) void*)g,
        (__attribute__((address_space(3))) void*)l,
        16, 0, 0);
}

// ---------------- Kernel 1: bilinear sampling -> colT bf16  (+ wconv fold) --
// Blocks 0..511: col. Block = (b, dg, cq of 16 ch, 8-row band). x slab
// (16ch x 12rows x 64w) staged as bf16 4-ch packs (24KB LDS); corners are
// ds_read_b64. Each lane owns a contiguous 32B colT chunk per (h,kk).
// Blocks 512..1087: weight repack fp32 -> bf16 (block 512 also zeroes partials).
__global__ __launch_bounds__(256) void col_kernel(const float* __restrict__ x,
                                                  const float* __restrict__ shp,
                                                  const float* __restrict__ woff,
                                                  unsigned short* __restrict__ colT,
                                                  const float* __restrict__ wd,
                                                  unsigned short* __restrict__ Wb,
                                                  float* __restrict__ partials) {
    __shared__ __align__(16) unsigned short xt[4 * 12 * 64 * 4];  // [c4g][row][w][c4] bf16 = 24KB

    int bid = blockIdx.x;
    int tid = threadIdx.x;

    if (bid >= 512) {
        if (bid == 512) partials[tid] = 0.f;       // 256 floats = [128][2]
        // ---- folded wconv: 576 blocks x 1024 elements ----
        int base = (bid - 512) * 1024 + tid * 4;   // 589,824 total
        unsigned short t[4];
        #pragma unroll
        for (int u = 0; u < 4; ++u) {
            int idx = base + u;
            int o  = idx / KT;
            int r  = idx % KT;
            int kk = r >> 8;
            int c  = r & 255;
            t[u] = f2bf(wd[o * KT + c * KKN + kk]);
        }
        *(uint2*)&Wb[base] = *(const uint2*)t;
        return;
    }

    int band  = bid & 7;             // 8-row band
    int cq    = (bid >> 3) & 3;      // 16-ch quarter of the dg's 64
    int dg    = (bid >> 5) & 3;
    int b     = bid >> 7;
    int h0    = band * 8;
    int lane  = tid & 63;            // = w in compute phase
    int wv    = tid >> 6;            // wave -> 2 rows of the band

    // ---- stage x slab: 12288 values (16ch x 12rows x 64w), fp32->bf16 ------
    const float* xg = x + (size_t)(b * CCH + dg * CG + cq * 16) * HWSZ;
    #pragma unroll 1
    for (int ii = 0; ii < 6; ++ii) {
        float v[8]; int la[8];
        #pragma unroll
        for (int u = 0; u < 8; ++u) {
            int idx = (ii * 8 + u) * 256 + tid;     // 0..12287
            int j   = idx / 768;                    // channel 0..15
            int rem = idx - j * 768;
            int r   = rem >> 6;                     // row 0..11
            int w   = rem & 63;
            int gr  = min(max(h0 - 2 + r, 0), HH - 1);
            v[u]  = xg[(size_t)j * HWSZ + gr * 64 + w];
            la[u] = ((j >> 2) * 12 + r) * 256 + w * 4 + (j & 3);   // ushort index
        }
        #pragma unroll
        for (int u = 0; u < 8; ++u) xt[la[u]] = f2bf(v[u]);
    }
    __syncthreads();

    const char* xtb = (const char*)xt;

    // ---- compute: wave wv handles rows h0+wv*2 .. h0+wv*2+1 ----
    #pragma unroll 1
    for (int hr = 0; hr < 2; ++hr) {
        int h  = h0 + wv * 2 + hr;
        int hw = h * 64 + lane;
        float s0 = shp[(b * 4 + 0) * HWSZ + hw];
        float s1 = shp[(b * 4 + 1) * HWSZ + hw];
        float s2 = shp[(b * 4 + 2) * HWSZ + hw];
        float s3 = shp[(b * 4 + 3) * HWSZ + hw];

        unsigned short* rowp = colT + (size_t)(b * HWSZ + hw) * KT + dg * CG + cq * 16;

        #pragma unroll
        for (int kk = 0; kk < KKN; ++kk) {
            const float* wo = woff + (dg * 18 + kk * 2) * 4;
            float dy = wo[0] * s0 + wo[1] * s1 + wo[2] * s2 + wo[3] * s3;
            float dx = wo[4] * s0 + wo[5] * s1 + wo[6] * s2 + wo[7] * s3;

            int ky = kk / 3, kx = kk % 3;
            float y  = (float)(h - 1 + ky) + dy;
            float xs = (float)(lane - 1 + kx) + dx;
            float y0f = floorf(y), x0f = floorf(xs);
            float wy1 = y - y0f,  wx1 = xs - x0f;
            float wy0 = 1.f - wy1, wx0 = 1.f - wx1;
            int iy0 = (int)y0f, ix0 = (int)x0f;
            int iy1 = iy0 + 1,  ix1 = ix0 + 1;
            bool vy0 = (iy0 >= 0) && (iy0 < HH);
            bool vy1 = (iy1 >= 0) && (iy1 < HH);
            bool vx0 = (ix0 >= 0) && (ix0 < WWD);
            bool vx1 = (ix1 >= 0) && (ix1 < WWD);
            float w00 = (vy0 && vx0) ? wy0 * wx0 : 0.f;
            float w01 = (vy0 && vx1) ? wy0 * wx1 : 0.f;
            float w10 = (vy1 && vx0) ? wy1 * wx0 : 0.f;
            float w11 = (vy1 && vx1) ? wy1 * wx1 : 0.f;
            int cy0 = min(max(iy0, 0), HH - 1);
            int cy1 = min(max(iy1, 0), HH - 1);
            int cx0 = min(max(ix0, 0), WWD - 1);
            int cx1 = min(max(ix1, 0), WWD - 1);
            int ty0 = min(max(cy0 - (h0 - 2), 0), 11);   // clamp = safety for huge offsets
            int ty1 = min(max(cy1 - (h0 - 2), 0), 11);
            int a00 = (ty0 * 64 + cx0) * 8;              // 8 B per 4-ch pack
            int a01 = (ty0 * 64 + cx1) * 8;
            int a10 = (ty1 * 64 + cx0) * 8;
            int a11 = (ty1 * 64 + cx1) * 8;

            unsigned short tmp[16];
            #pragma unroll
            for (int c4g = 0; c4g < 4; ++c4g) {
                int base = c4g * 6144;                   // 12 rows * 64 w * 8 B
                const uint2 q00 = *(const uint2*)(xtb + base + a00);
                const uint2 q01 = *(const uint2*)(xtb + base + a01);
                const uint2 q10 = *(const uint2*)(xtb + base + a10);
                const uint2 q11 = *(const uint2*)(xtb + base + a11);
                float r0 = w00 * bflo(q00.x) + w01 * bflo(q01.x) + w10 * bflo(q10.x) + w11 * bflo(q11.x);
                float r1 = w00 * bfhi(q00.x) + w01 * bfhi(q01.x) + w10 * bfhi(q10.x) + w11 * bfhi(q11.x);
                float r2 = w00 * bflo(q00.y) + w01 * bflo(q01.y) + w10 * bflo(q10.y) + w11 * bflo(q11.y);
                float r3 = w00 * bfhi(q00.y) + w01 * bfhi(q01.y) + w10 * bfhi(q10.y) + w11 * bfhi(q11.y);
                tmp[c4g * 4 + 0] = f2bf(r0);
                tmp[c4g * 4 + 1] = f2bf(r1);
                tmp[c4g * 4 + 2] = f2bf(r2);
                tmp[c4g * 4 + 3] = f2bf(r3);
            }
            uint4* dst = (uint4*)(rowp + kk * 256);
            const uint4* src = (const uint4*)tmp;
            dst[0] = src[0];
            dst[1] = src[1];
        }
    }
}

// ---------------- Kernel 2: bf16 MFMA GEMM + GN stats + grid.sync + apply ---
// 64m x 128n tile, 256 threads (4 waves 2x2, wave = 32m x 64n = 2x4 MFMA),
// BK=64, XOR bank swizzle + XCD swizzle. After the K-loop: per-(b,group)
// s1/s2 -> partials (device atomics), grid-wide sync, then each block
// normalizes its OWN acc registers and writes out directly (no G buffer).
__global__ __launch_bounds__(256) void gemm_kernel(const unsigned short* __restrict__ Wb,
                                                   const unsigned short* __restrict__ colT,
                                                   float* __restrict__ partials,
                                                   const float* __restrict__ gamma,
                                                   const float* __restrict__ beta,
                                                   float* __restrict__ out) {
    __shared__ __align__(16) short As[64 * 64];    // 8 KB
    __shared__ __align__(16) short Bs[128 * 64];   // 16 KB
    __shared__ float sred[16];                     // [group 0..7][s1,s2]

    int tid  = threadIdx.x;
    int lane = tid & 63;
    int wv   = tid >> 6;
    int wm   = wv >> 1;           // 0..1 -> 32-row m-slab
    int wn   = wv & 1;            // 0..1 -> 64-col n-slab

    // XCD-aware decode: xcd = idx&7 owns n-tiles [xcd*16, xcd*16+16)
    int idx  = blockIdx.x;        // 0..511
    int xcd  = idx & 7;
    int j2   = idx >> 3;          // 0..63
    int n0   = (xcd * 16 + (j2 >> 2)) * 128;
    int m0   = (j2 & 3) * 64;

    if (tid < 16) sred[tid] = 0.f;   // ordered by first __syncthreads below

    // Staging decode: thread tid -> chunk; row r=tid>>3, slot s=tid&7,
    // holds global k-chunk k = s ^ (r&7).
    int r_a = tid >> 3;
    int s_a = tid & 7;
    int k_a = (s_a ^ (r_a & 7)) * 8;

    f32x4 acc[2][4] = {};

    int quad = lane >> 4;
    int lrow = lane & 15;
    int sw   = lrow & 7;          // read-side XOR (row&7 == lrow&7 here)

    for (int kt = 0; kt < KT; kt += 64) {
        #pragma unroll
        for (int u = 0; u < 2; ++u) {
            int rr = u * 32 + r_a;
            gl_lds16(Wb + (size_t)(m0 + rr) * KT + kt + k_a,
                     (short*)As + (u * 256 + tid) * 8);
        }
        #pragma unroll
        for (int u = 0; u < 4; ++u) {
            int rr = u * 32 + r_a;
            gl_lds16(colT + (size_t)(n0 + rr) * KT + kt + k_a,
                     (short*)Bs + (u * 256 + tid) * 8);
        }
        __syncthreads();   // drains vmcnt(0) -> LDS data visible

        #pragma unroll
        for (int kb = 0; kb < 2; ++kb) {
            int slot = (kb * 4 + quad) ^ sw;
            short8 a[2], b[4];
            #pragma unroll
            for (int i = 0; i < 2; ++i)
                a[i] = *(const short8*)&As[(wm * 32 + i * 16 + lrow) * 64 + slot * 8];
            #pragma unroll
            for (int j = 0; j < 4; ++j)
                b[j] = *(const short8*)&Bs[(wn * 64 + j * 16 + lrow) * 64 + slot * 8];
            #pragma unroll
            for (int i = 0; i < 2; ++i)
                #pragma unroll
                for (int j = 0; j < 4; ++j)
                    acc[i][j] = __builtin_amdgcn_mfma_f32_16x16x32_bf16(a[i], b[j], acc[i][j], 0, 0, 0);
        }
        __syncthreads();   // protect LDS before next stage
    }

    // GN partial sums from fp32 accs (lane's 4 rows lie in one group).
    #pragma unroll
    for (int i = 0; i < 2; ++i) {
        float s1 = 0.f, s2 = 0.f;
        #pragma unroll
        for (int j = 0; j < 4; ++j)
            #pragma unroll
            for (int r = 0; r < 4; ++r) {
                float v = acc[i][j][r];
                s1 += v;
                s2 += v * v;
            }
        #pragma unroll
        for (int off = 1; off < 16; off <<= 1) {
            s1 += __shfl_xor(s1, off);
            s2 += __shfl_xor(s2, off);
        }
        if (lrow == 0) {
            int gg = (wm * 32 + i * 16 + quad * 4) >> 3;   // 0..7
            atomicAdd(&sred[gg * 2],     s1);
            atomicAdd(&sred[gg * 2 + 1], s2);
        }
    }
    __syncthreads();
    int b  = n0 >> 12;
    if (tid < 8) {
        int g0 = m0 >> 3;
        atomicAdd(&partials[(b * 32 + g0 + tid) * 2],     sred[tid * 2]);
        atomicAdd(&partials[(b * 32 + g0 + tid) * 2 + 1], sred[tid * 2 + 1]);
    }

    // ---- grid-wide sync: all partials complete ----
    cg::this_grid().sync();

    // ---- apply GN + ReLU from registers, write out [b][o][hw] ----
    const float invN = 1.f / 32768.f;
    int hwb = (n0 & 4095) + wn * 64;
    #pragma unroll
    for (int i = 0; i < 2; ++i) {
        int m = m0 + wm * 32 + i * 16 + quad * 4;
        int g = m >> 3;
        volatile const float* pp = partials + (b * 32 + g) * 2;
        float p1 = pp[0];
        float p2 = pp[1];
        float mean = p1 * invN;
        float var  = p2 * invN - mean * mean;
        float rstd = rsqrtf(var + EPSV);
        #pragma unroll
        for (int r = 0; r < 4; ++r) {
            int o = m + r;
            float ga = gamma[o] * rstd;
            float be = beta[o] - mean * ga;
            float* orow = out + ((size_t)(b * CCH + o) << 12);
            #pragma unroll
            for (int j = 0; j < 4; ++j) {
                int hw = hwb + j * 16 + lrow;
                orow[hw] = fmaxf(0.f, acc[i][j][r] * ga + be);
            }
        }
    }
}

extern "C" void kernel_launch(void* const* d_in, const int* in_sizes, int n_in,
                              void* d_out, int out_size, void* d_ws, size_t ws_size,
                              hipStream_t stream) {
    const float* x     = (const float*)d_in[0];
    const float* shp   = (const float*)d_in[1];
    const float* woff  = (const float*)d_in[2];
    const float* wdef  = (const float*)d_in[3];
    const float* gamma = (const float*)d_in[4];
    const float* beta  = (const float*)d_in[5];
    float* out = (float*)d_out;

    char* ws = (char*)d_ws;
    unsigned short* colT = (unsigned short*)(ws + WS_COLT);
    unsigned short* Wb   = (unsigned short*)(ws + WS_WB);
    float* partials      = (float*)(ws + WS_PART);

    col_kernel<<<1088, 256, 0, stream>>>(x, shp, woff, colT, wdef, Wb, partials);

    void* args[] = {(void*)&Wb, (void*)&colT, (void*)&partials,
                    (void*)&gamma, (void*)&beta, (void*)&out};
    hipLaunchCooperativeKernel((void*)gemm_kernel, dim3(512), dim3(256),
                               args, 0, stream);
}

// Round 9
// 134.554 us; speedup vs baseline: 1.4874x; 1.4874x over previous
//
#include <hip/hip_runtime.h>
#include <stdint.h>

// Problem constants
#define BB   4
#define CCH  256
#define HH   64
#define WWD  64
#define HWSZ 4096          // H*W
#define DGRP 4
#define CG   64            // C / DG
#define KKN  9
#define KT   2304          // C * KK  (k index = kk*256 + c)
#define NND  16384         // B*H*W
#define GNG  32
#define EPSV 1e-5f

// Workspace layout (bytes):
//  colT     bf16 [NND][KT]            @ 0          size 75,497,472
//  Wb       bf16 [256][KT]            @ 75497472   size  1,179,648
//  G        bf16 [256][NND]           @ 76677120   size  8,388,608
//  partials f32  [128][2] (s1,s2)     @ 93454336   size      1,024
#define WS_COLT  0
#define WS_WB    75497472
#define WS_G     76677120
#define WS_PART  93454336

typedef __attribute__((ext_vector_type(8))) short short8;
typedef __attribute__((ext_vector_type(4))) float f32x4;

__device__ inline unsigned short f2bf(float f) {
    union { float f; unsigned u; } v; v.f = f;
    unsigned u = v.u;
    return (unsigned short)((u + 0x7FFFu + ((u >> 16) & 1u)) >> 16);  // RNE
}

__device__ inline float bflo(unsigned u) {   // low bf16 of a packed u32 -> f32
    union { unsigned u; float f; } v; v.u = u << 16; return v.f;
}
__device__ inline float bfhi(unsigned u) {   // high bf16 -> f32
    union { unsigned u; float f; } v; v.u = u & 0xffff0000u; return v.f;
}

__device__ inline void gl_lds16(const void* g, void* l) {
    __builtin_amdgcn_global_load_lds(
        (const __attribute__((address_space(1))) void*)g,
        (__attribute__((address_space(3))) void*)l,
        16, 0, 0);
}

// ---------------- Kernel 1: bilinear sampling -> colT bf16  (+ wconv fold) --
// Blocks 0..511: col. Block = (b, dg, cq of 16 ch, 8-row band). x slab
// (16ch x 12rows x 64w) staged as bf16 4-ch packs (24KB LDS); corners are
// ds_read_b64. Each lane owns a contiguous 32B colT chunk per (h,kk).
// Blocks 512..1087: weight repack fp32 -> bf16 (block 512 also zeroes partials).
__global__ __launch_bounds__(256) void col_kernel(const float* __restrict__ x,
                                                  const float* __restrict__ shp,
                                                  const float* __restrict__ woff,
                                                  unsigned short* __restrict__ colT,
                                                  const float* __restrict__ wd,
                                                  unsigned short* __restrict__ Wb,
                                                  float* __restrict__ partials) {
    __shared__ __align__(16) unsigned short xt[4 * 12 * 64 * 4];  // [c4g][row][w][c4] bf16 = 24KB

    int bid = blockIdx.x;
    int tid = threadIdx.x;

    if (bid >= 512) {
        if (bid == 512) partials[tid] = 0.f;       // 256 floats = [128][2]
        // ---- folded wconv: 576 blocks x 1024 elements ----
        int base = (bid - 512) * 1024 + tid * 4;   // 589,824 total
        unsigned short t[4];
        #pragma unroll
        for (int u = 0; u < 4; ++u) {
            int idx = base + u;
            int o  = idx / KT;
            int r  = idx % KT;
            int kk = r >> 8;
            int c  = r & 255;
            t[u] = f2bf(wd[o * KT + c * KKN + kk]);
        }
        *(uint2*)&Wb[base] = *(const uint2*)t;
        return;
    }

    int band  = bid & 7;             // 8-row band
    int cq    = (bid >> 3) & 3;      // 16-ch quarter of the dg's 64
    int dg    = (bid >> 5) & 3;
    int b     = bid >> 7;
    int h0    = band * 8;
    int lane  = tid & 63;            // = w in compute phase
    int wv    = tid >> 6;            // wave -> 2 rows of the band

    // ---- stage x slab: 12288 values (16ch x 12rows x 64w), fp32->bf16 ------
    const float* xg = x + (size_t)(b * CCH + dg * CG + cq * 16) * HWSZ;
    #pragma unroll 1
    for (int ii = 0; ii < 6; ++ii) {
        float v[8]; int la[8];
        #pragma unroll
        for (int u = 0; u < 8; ++u) {
            int idx = (ii * 8 + u) * 256 + tid;     // 0..12287
            int j   = idx / 768;                    // channel 0..15
            int rem = idx - j * 768;
            int r   = rem >> 6;                     // row 0..11
            int w   = rem & 63;
            int gr  = min(max(h0 - 2 + r, 0), HH - 1);
            v[u]  = xg[(size_t)j * HWSZ + gr * 64 + w];
            la[u] = ((j >> 2) * 12 + r) * 256 + w * 4 + (j & 3);   // ushort index
        }
        #pragma unroll
        for (int u = 0; u < 8; ++u) xt[la[u]] = f2bf(v[u]);
    }
    __syncthreads();

    const char* xtb = (const char*)xt;

    // ---- compute: wave wv handles rows h0+wv*2 .. h0+wv*2+1 ----
    #pragma unroll 1
    for (int hr = 0; hr < 2; ++hr) {
        int h  = h0 + wv * 2 + hr;
        int hw = h * 64 + lane;
        float s0 = shp[(b * 4 + 0) * HWSZ + hw];
        float s1 = shp[(b * 4 + 1) * HWSZ + hw];
        float s2 = shp[(b * 4 + 2) * HWSZ + hw];
        float s3 = shp[(b * 4 + 3) * HWSZ + hw];

        unsigned short* rowp = colT + (size_t)(b * HWSZ + hw) * KT + dg * CG + cq * 16;

        #pragma unroll
        for (int kk = 0; kk < KKN; ++kk) {
            const float* wo = woff + (dg * 18 + kk * 2) * 4;
            float dy = wo[0] * s0 + wo[1] * s1 + wo[2] * s2 + wo[3] * s3;
            float dx = wo[4] * s0 + wo[5] * s1 + wo[6] * s2 + wo[7] * s3;

            int ky = kk / 3, kx = kk % 3;
            float y  = (float)(h - 1 + ky) + dy;
            float xs = (float)(lane - 1 + kx) + dx;
            float y0f = floorf(y), x0f = floorf(xs);
            float wy1 = y - y0f,  wx1 = xs - x0f;
            float wy0 = 1.f - wy1, wx0 = 1.f - wx1;
            int iy0 = (int)y0f, ix0 = (int)x0f;
            int iy1 = iy0 + 1,  ix1 = ix0 + 1;
            bool vy0 = (iy0 >= 0) && (iy0 < HH);
            bool vy1 = (iy1 >= 0) && (iy1 < HH);
            bool vx0 = (ix0 >= 0) && (ix0 < WWD);
            bool vx1 = (ix1 >= 0) && (ix1 < WWD);
            float w00 = (vy0 && vx0) ? wy0 * wx0 : 0.f;
            float w01 = (vy0 && vx1) ? wy0 * wx1 : 0.f;
            float w10 = (vy1 && vx0) ? wy1 * wx0 : 0.f;
            float w11 = (vy1 && vx1) ? wy1 * wx1 : 0.f;
            int cy0 = min(max(iy0, 0), HH - 1);
            int cy1 = min(max(iy1, 0), HH - 1);
            int cx0 = min(max(ix0, 0), WWD - 1);
            int cx1 = min(max(ix1, 0), WWD - 1);
            int ty0 = min(max(cy0 - (h0 - 2), 0), 11);   // clamp = safety for huge offsets
            int ty1 = min(max(cy1 - (h0 - 2), 0), 11);
            int a00 = (ty0 * 64 + cx0) * 8;              // 8 B per 4-ch pack
            int a01 = (ty0 * 64 + cx1) * 8;
            int a10 = (ty1 * 64 + cx0) * 8;
            int a11 = (ty1 * 64 + cx1) * 8;

            unsigned short tmp[16];
            #pragma unroll
            for (int c4g = 0; c4g < 4; ++c4g) {
                int base = c4g * 6144;                   // 12 rows * 64 w * 8 B
                const uint2 q00 = *(const uint2*)(xtb + base + a00);
                const uint2 q01 = *(const uint2*)(xtb + base + a01);
                const uint2 q10 = *(const uint2*)(xtb + base + a10);
                const uint2 q11 = *(const uint2*)(xtb + base + a11);
                float r0 = w00 * bflo(q00.x) + w01 * bflo(q01.x) + w10 * bflo(q10.x) + w11 * bflo(q11.x);
                float r1 = w00 * bfhi(q00.x) + w01 * bfhi(q01.x) + w10 * bfhi(q10.x) + w11 * bfhi(q11.x);
                float r2 = w00 * bflo(q00.y) + w01 * bflo(q01.y) + w10 * bflo(q10.y) + w11 * bflo(q11.y);
                float r3 = w00 * bfhi(q00.y) + w01 * bfhi(q01.y) + w10 * bfhi(q10.y) + w11 * bfhi(q11.y);
                tmp[c4g * 4 + 0] = f2bf(r0);
                tmp[c4g * 4 + 1] = f2bf(r1);
                tmp[c4g * 4 + 2] = f2bf(r2);
                tmp[c4g * 4 + 3] = f2bf(r3);
            }
            uint4* dst = (uint4*)(rowp + kk * 256);
            const uint4* src = (const uint4*)tmp;
            dst[0] = src[0];
            dst[1] = src[1];
        }
    }
}

// ---------------- Kernel 2: bf16 MFMA GEMM + fused GN partial sums ----------
// 64m x 128n tile, 256 threads (4 waves 2x2, wave = 32m x 64n = 2x4 MFMA),
// BK=128 (18 K-iterations -> half the barrier drains of BK=64; LDS 48KB keeps
// 2 blocks/CU). XOR bank swizzle: row r 16B-chunk k stored at slot k^(r&15)
// -> fragment reads 2-way (free). XCD swizzle for colT L2 locality.
__global__ __launch_bounds__(256) void gemm_kernel(const unsigned short* __restrict__ Wb,
                                                   const unsigned short* __restrict__ colT,
                                                   unsigned short* __restrict__ G,
                                                   float* __restrict__ partials) {
    __shared__ __align__(16) short As[64 * 128];   // 16 KB
    __shared__ __align__(16) short Bs[128 * 128];  // 32 KB
    __shared__ float sred[16];                     // [group 0..7][s1,s2]

    int tid  = threadIdx.x;
    int lane = tid & 63;
    int wv   = tid >> 6;
    int wm   = wv >> 1;           // 0..1 -> 32-row m-slab
    int wn   = wv & 1;            // 0..1 -> 64-col n-slab

    // XCD-aware decode: xcd = idx&7 owns n-tiles [xcd*16, xcd*16+16)
    int idx  = blockIdx.x;        // 0..511
    int xcd  = idx & 7;
    int j2   = idx >> 3;          // 0..63
    int n0   = (xcd * 16 + (j2 >> 2)) * 128;
    int m0   = (j2 & 3) * 64;

    if (tid < 16) sred[tid] = 0.f;   // ordered by first __syncthreads below

    f32x4 acc[2][4] = {};

    int quad = lane >> 4;
    int lrow = lane & 15;

    for (int kt = 0; kt < KT; kt += 128) {
        // A: 1024 chunks (64 rows x 16 slots), 4 per thread.
        // chunk e: row r=e>>4, slot s=e&15 holds global k-chunk s^(r&15).
        #pragma unroll
        for (int u = 0; u < 4; ++u) {
            int e = u * 256 + tid;
            int r = e >> 4;
            int k = ((e & 15) ^ (r & 15)) * 8;
            gl_lds16(Wb + (size_t)(m0 + r) * KT + kt + k, (short*)As + e * 8);
        }
        // B: 2048 chunks (128 rows x 16 slots), 8 per thread.
        #pragma unroll
        for (int u = 0; u < 8; ++u) {
            int e = u * 256 + tid;
            int r = e >> 4;
            int k = ((e & 15) ^ (r & 15)) * 8;
            gl_lds16(colT + (size_t)(n0 + r) * KT + kt + k, (short*)Bs + e * 8);
        }
        __syncthreads();   // drains vmcnt(0) -> LDS data visible

        #pragma unroll
        for (int kb = 0; kb < 4; ++kb) {
            int slot = (kb * 4 + quad) ^ lrow;   // row&15 == lrow for all frag rows
            short8 a[2], b[4];
            #pragma unroll
            for (int i = 0; i < 2; ++i)
                a[i] = *(const short8*)&As[(wm * 32 + i * 16 + lrow) * 128 + slot * 8];
            #pragma unroll
            for (int j = 0; j < 4; ++j)
                b[j] = *(const short8*)&Bs[(wn * 64 + j * 16 + lrow) * 128 + slot * 8];
            #pragma unroll
            for (int i = 0; i < 2; ++i)
                #pragma unroll
                for (int j = 0; j < 4; ++j)
                    acc[i][j] = __builtin_amdgcn_mfma_f32_16x16x32_bf16(a[i], b[j], acc[i][j], 0, 0, 0);
        }
        __syncthreads();   // protect LDS before next stage
    }

    // Epilogue 1: write G (bf16).  D[row = quad*4 + r][col = lane&15]
    #pragma unroll
    for (int i = 0; i < 2; ++i) {
        int m = m0 + wm * 32 + i * 16 + quad * 4;
        #pragma unroll
        for (int j = 0; j < 4; ++j) {
            int n = n0 + wn * 64 + j * 16 + lrow;
            #pragma unroll
            for (int r = 0; r < 4; ++r)
                G[(size_t)(m + r) * NND + n] = f2bf(acc[i][j][r]);
        }
    }

    // Epilogue 2: GN partial sums from fp32 accs (lane's 4 rows in one group).
    #pragma unroll
    for (int i = 0; i < 2; ++i) {
        float s1 = 0.f, s2 = 0.f;
        #pragma unroll
        for (int j = 0; j < 4; ++j)
            #pragma unroll
            for (int r = 0; r < 4; ++r) {
                float v = acc[i][j][r];
                s1 += v;
                s2 += v * v;
            }
        #pragma unroll
        for (int off = 1; off < 16; off <<= 1) {
            s1 += __shfl_xor(s1, off);
            s2 += __shfl_xor(s2, off);
        }
        if (lrow == 0) {
            int gg = (wm * 32 + i * 16 + quad * 4) >> 3;   // 0..7
            atomicAdd(&sred[gg * 2],     s1);
            atomicAdd(&sred[gg * 2 + 1], s2);
        }
    }
    __syncthreads();
    if (tid < 8) {
        int b  = n0 >> 12;
        int g0 = m0 >> 3;
        atomicAdd(&partials[(b * 32 + g0 + tid) * 2],     sred[tid * 2]);
        atomicAdd(&partials[(b * 32 + g0 + tid) * 2 + 1], sred[tid * 2 + 1]);
    }
}

// ---------------- Kernel 3: GN apply + ReLU, bf16 G -> fp32 out -------------
__global__ __launch_bounds__(256) void gn_apply_kernel(const unsigned short* __restrict__ G,
                                                       const float* __restrict__ partials,
                                                       const float* __restrict__ gamma,
                                                       const float* __restrict__ beta,
                                                       float* __restrict__ out) {
    int idx = blockIdx.x * 256 + threadIdx.x;   // 1,048,576 groups of 4
    int hw4 = idx & 1023;
    int o   = (idx >> 10) & 255;
    int b   = idx >> 18;
    int g   = o >> 3;
    const float invN = 1.f / 32768.f;
    float p1 = partials[(b * 32 + g) * 2];
    float p2 = partials[(b * 32 + g) * 2 + 1];
    float mean = p1 * invN;
    float var  = p2 * invN - mean * mean;
    float rstd = rsqrtf(var + EPSV);
    float ga = gamma[o], be = beta[o];
    const uint2 q = *(const uint2*)&G[(size_t)o * NND + b * HWSZ + hw4 * 4];
    float4 r;
    r.x = fmaxf(0.f, (bflo(q.x) - mean) * rstd * ga + be);
    r.y = fmaxf(0.f, (bfhi(q.x) - mean) * rstd * ga + be);
    r.z = fmaxf(0.f, (bflo(q.y) - mean) * rstd * ga + be);
    r.w = fmaxf(0.f, (bfhi(q.y) - mean) * rstd * ga + be);
    *(float4*)&out[(size_t)(b * CCH + o) * HWSZ + hw4 * 4] = r;
}

extern "C" void kernel_launch(void* const* d_in, const int* in_sizes, int n_in,
                              void* d_out, int out_size, void* d_ws, size_t ws_size,
                              hipStream_t stream) {
    const float* x     = (const float*)d_in[0];
    const float* shp   = (const float*)d_in[1];
    const float* woff  = (const float*)d_in[2];
    const float* wdef  = (const float*)d_in[3];
    const float* gamma = (const float*)d_in[4];
    const float* beta  = (const float*)d_in[5];
    float* out = (float*)d_out;

    char* ws = (char*)d_ws;
    unsigned short* colT = (unsigned short*)(ws + WS_COLT);
    unsigned short* Wb   = (unsigned short*)(ws + WS_WB);
    unsigned short* G    = (unsigned short*)(ws + WS_G);
    float* partials      = (float*)(ws + WS_PART);

    col_kernel<<<1088, 256, 0, stream>>>(x, shp, woff, colT, wdef, Wb, partials);
    gemm_kernel<<<512, 256, 0, stream>>>(Wb, colT, G, partials);
    gn_apply_kernel<<<4096, 256, 0, stream>>>(G, partials, gamma, beta, out);
}